// Round 1
// baseline (1313.850 us; speedup 1.0000x reference)
//
#include <hip/hip_runtime.h>
#include <hip/hip_bf16.h>

#define T_TOK 4096
#define HID 2048
#define NE 32
#define FF 768
#define TOPK 4

typedef __bf16 bf16;
typedef __bf16 bf16x4 __attribute__((ext_vector_type(4)));
typedef __bf16 bf16x8 __attribute__((ext_vector_type(8)));
typedef float f32x4 __attribute__((ext_vector_type(4)));

// ---------------- Router: logits, softmax, top-4, counts ----------------
__global__ __launch_bounds__(256) void router_kernel(
    const float* __restrict__ x, const float* __restrict__ gw,
    float* __restrict__ logits_out, int* __restrict__ topi,
    float* __restrict__ topw, int* __restrict__ counts)
{
    const int t = blockIdx.x;
    __shared__ float xs[HID];
    __shared__ float lg[NE];
    __shared__ float ps[NE];
    const float4* xr = (const float4*)(x + (size_t)t * HID);
    float4* xs4 = (float4*)xs;
    for (int i = threadIdx.x; i < HID / 4; i += 256) xs4[i] = xr[i];
    __syncthreads();

    const int e = threadIdx.x >> 3;   // 0..31
    const int part = threadIdx.x & 7; // 8 threads per expert
    const float4* gr = (const float4*)(gw + (size_t)e * HID + part * 256);
    const float4* xp = (const float4*)(xs + part * 256);
    float sum = 0.f;
#pragma unroll 8
    for (int i = 0; i < 64; ++i) {
        float4 g = gr[i], v = xp[i];
        sum += g.x * v.x + g.y * v.y + g.z * v.z + g.w * v.w;
    }
    sum += __shfl_down(sum, 4, 8);
    sum += __shfl_down(sum, 2, 8);
    sum += __shfl_down(sum, 1, 8);
    if (part == 0) { lg[e] = sum; logits_out[(size_t)t * NE + e] = sum; }
    __syncthreads();

    if (threadIdx.x == 0) {
        float mx = lg[0];
        for (int i = 1; i < NE; ++i) mx = fmaxf(mx, lg[i]);
        for (int i = 0; i < NE; ++i) ps[i] = __expf(lg[i] - mx);
        float tw[TOPK]; int ti[TOPK]; float ts = 0.f;
        for (int k = 0; k < TOPK; ++k) {
            float best = -1.f; int bi = 0;
            for (int i = 0; i < NE; ++i)
                if (ps[i] > best) { best = ps[i]; bi = i; }  // first index wins ties
            tw[k] = best; ti[k] = bi; ps[bi] = -2.f; ts += best;
        }
        const float inv = 1.f / ts;
        for (int k = 0; k < TOPK; ++k) {
            topi[t * TOPK + k] = ti[k];
            topw[t * TOPK + k] = tw[k] * inv;
            atomicAdd(&counts[ti[k]], 1);
        }
    }
}

// ---------------- Offsets: exclusive scan over 32 counts ----------------
__global__ void offsets_kernel(const int* __restrict__ counts,
                               int* __restrict__ offs, int* __restrict__ cursors)
{
    if (threadIdx.x == 0) {
        int acc = 0;
        for (int e2 = 0; e2 < NE; ++e2) { offs[e2] = acc; acc += counts[e2]; cursors[e2] = 0; }
    }
}

// ---------------- Scatter tokens into expert-contiguous slots ----------------
__global__ __launch_bounds__(256) void scatter_kernel(
    const int* __restrict__ topi, const float* __restrict__ topw,
    const int* __restrict__ offs, int* __restrict__ cursors,
    int* __restrict__ slot_token, float* __restrict__ slot_w)
{
    int t = blockIdx.x * 256 + threadIdx.x;
    if (t >= T_TOK) return;
#pragma unroll
    for (int k = 0; k < TOPK; ++k) {
        int e2 = topi[t * TOPK + k];
        int pos = atomicAdd(&cursors[e2], 1);
        int idx = offs[e2] + pos;
        slot_token[idx] = t;
        slot_w[idx] = topw[t * TOPK + k];
    }
}

// ---------------- Fused gate|up grouped GEMM (bf16 MFMA) ----------------
// grid: x = nt (0..11: 0-5 gate, 6-11 up), y = mt (0..31), z = expert
__global__ __launch_bounds__(256) void gemm_gu_kernel(
    const float* __restrict__ x, const float* __restrict__ wg,
    const float* __restrict__ wu, const int* __restrict__ slot_token,
    const int* __restrict__ offs, const int* __restrict__ counts,
    bf16* __restrict__ GU)
{
    const int nt = blockIdx.x;
    const int mt = blockIdx.y;
    const int e  = blockIdx.z;
    const int cnt = counts[e];
    if (mt * 128 >= cnt) return;
    const int off = offs[e];
    const float* B = (nt < 6 ? wg : wu) + (size_t)e * HID * FF + (nt % 6) * 128;

    __shared__ bf16 As[128][40];
    __shared__ bf16 Bs[128][40];
    __shared__ int toks[128];

    const int tid = threadIdx.x;
    if (tid < 128) {
        int row = mt * 128 + tid;
        toks[tid] = (row < cnt) ? slot_token[off + row] : -1;
    }
    __syncthreads();

    const int lane = tid & 63;
    const int w  = tid >> 6;
    const int wm = (w & 1) * 64;
    const int wn = (w >> 1) * 64;
    const int fr = lane & 15;
    const int kq = lane >> 4;

    f32x4 acc[4][4];
#pragma unroll
    for (int i = 0; i < 4; ++i)
#pragma unroll
        for (int j = 0; j < 4; ++j) acc[i][j] = {0.f, 0.f, 0.f, 0.f};

    const int am = tid >> 3;  // row base 0..31 (+32p)
    const int ak = tid & 7;   // float4 index in 32-float chunk
    const int bn = tid & 127;
    const int bkh = (tid >> 7) * 16;

    bool aval[4]; const float* aptr[4];
#pragma unroll
    for (int p = 0; p < 4; ++p) {
        int tok = toks[am + p * 32];
        aval[p] = tok >= 0;
        aptr[p] = x + (size_t)(tok < 0 ? 0 : tok) * HID + ak * 4;
    }
    const float* bbase = B + (size_t)bkh * FF + bn;

    for (int kk = 0; kk < HID; kk += 32) {
        __syncthreads();
        // A: gathered x rows fp32 -> bf16, layout As[m][k]
#pragma unroll
        for (int p = 0; p < 4; ++p) {
            float4 v = make_float4(0.f, 0.f, 0.f, 0.f);
            if (aval[p]) v = *(const float4*)(aptr[p] + kk);
            bf16x4 b4 = {(bf16)v.x, (bf16)v.y, (bf16)v.z, (bf16)v.w};
            *(bf16x4*)&As[am + p * 32][ak * 4] = b4;
        }
        // B: transpose-stage fp32 [k][n] -> bf16 Bs[n][k]
        {
            const float* bp = bbase + (size_t)kk * FF;
            bf16 tmp[16] __attribute__((aligned(16)));
#pragma unroll
            for (int j = 0; j < 16; ++j) tmp[j] = (bf16)bp[(size_t)j * FF];
            *(bf16x8*)&Bs[bn][bkh]     = *(bf16x8*)tmp;
            *(bf16x8*)&Bs[bn][bkh + 8] = *(bf16x8*)(tmp + 8);
        }
        __syncthreads();
        bf16x8 a[4], b[4];
#pragma unroll
        for (int i = 0; i < 4; ++i) a[i] = *(const bf16x8*)&As[wm + i * 16 + fr][kq * 8];
#pragma unroll
        for (int j = 0; j < 4; ++j) b[j] = *(const bf16x8*)&Bs[wn + j * 16 + fr][kq * 8];
#pragma unroll
        for (int i = 0; i < 4; ++i)
#pragma unroll
            for (int j = 0; j < 4; ++j)
                acc[i][j] = __builtin_amdgcn_mfma_f32_16x16x32_bf16(a[i], b[j], acc[i][j], 0, 0, 0);
    }

    const int colBase = nt * 128 + wn;
#pragma unroll
    for (int i = 0; i < 4; ++i) {
#pragma unroll
        for (int r = 0; r < 4; ++r) {
            int mloc = wm + i * 16 + kq * 4 + r;
            int row = mt * 128 + mloc;
            if (row < cnt) {
                bf16* dst = GU + (size_t)(off + row) * (2 * FF) + colBase;
#pragma unroll
                for (int j = 0; j < 4; ++j)
                    dst[j * 16 + fr] = (bf16)acc[i][j][r];
            }
        }
    }
}

// ---------------- SiLU(g) * u ----------------
__global__ __launch_bounds__(256) void silu_mul_kernel(
    const bf16* __restrict__ GU, bf16* __restrict__ hdn)
{
    size_t idx = ((size_t)blockIdx.x * 256 + threadIdx.x) * 4;
    size_t s = idx / FF;
    int f = (int)(idx % FF);
    const bf16* gp = GU + s * (2 * FF) + f;
    bf16x4 g4 = *(const bf16x4*)gp;
    bf16x4 u4 = *(const bf16x4*)(gp + FF);
    bf16x4 o;
#pragma unroll
    for (int i = 0; i < 4; ++i) {
        float g = (float)g4[i], u = (float)u4[i];
        float sl = g / (1.f + __expf(-g));
        o[i] = (bf16)(sl * u);
    }
    *(bf16x4*)(hdn + s * FF + f) = o;
}

// ---------------- Down GEMM + weighted atomic scatter-add ----------------
// grid: x = nt (0..15), y = mt (0..31), z = expert
__global__ __launch_bounds__(256) void gemm_down_kernel(
    const bf16* __restrict__ hdn, const float* __restrict__ wd,
    const int* __restrict__ slot_token, const float* __restrict__ slot_w,
    const int* __restrict__ offs, const int* __restrict__ counts,
    float* __restrict__ out)
{
    const int nt = blockIdx.x;
    const int mt = blockIdx.y;
    const int e  = blockIdx.z;
    const int cnt = counts[e];
    if (mt * 128 >= cnt) return;
    const int off = offs[e];
    const float* B = wd + (size_t)e * FF * HID + nt * 128;

    __shared__ bf16 As[128][40];
    __shared__ bf16 Bs[128][40];
    __shared__ int toks[128];
    __shared__ float wts[128];

    const int tid = threadIdx.x;
    if (tid < 128) {
        int row = mt * 128 + tid;
        if (row < cnt) { toks[tid] = slot_token[off + row]; wts[tid] = slot_w[off + row]; }
        else           { toks[tid] = 0; wts[tid] = 0.f; }
    }
    __syncthreads();

    const int lane = tid & 63;
    const int w  = tid >> 6;
    const int wm = (w & 1) * 64;
    const int wn = (w >> 1) * 64;
    const int fr = lane & 15;
    const int kq = lane >> 4;

    f32x4 acc[4][4];
#pragma unroll
    for (int i = 0; i < 4; ++i)
#pragma unroll
        for (int j = 0; j < 4; ++j) acc[i][j] = {0.f, 0.f, 0.f, 0.f};

    const int am = tid >> 2;  // 0..63 (+64p)
    const int ac = tid & 3;   // 16B chunk
    const int bn = tid & 127;
    const int bkh = (tid >> 7) * 16;

    bool aval[2]; const bf16* aptr[2];
#pragma unroll
    for (int p = 0; p < 2; ++p) {
        int row = mt * 128 + am + p * 64;
        aval[p] = row < cnt;
        aptr[p] = hdn + (size_t)(off + (row < cnt ? row : 0)) * FF + ac * 8;
    }
    const float* bbase = B + (size_t)bkh * HID + bn;

    for (int kk = 0; kk < FF; kk += 32) {
        __syncthreads();
#pragma unroll
        for (int p = 0; p < 2; ++p) {
            uint4 v = make_uint4(0, 0, 0, 0);
            if (aval[p]) v = *(const uint4*)(aptr[p] + kk);
            *(uint4*)&As[am + p * 64][ac * 8] = v;
        }
        {
            const float* bp = bbase + (size_t)kk * HID;
            bf16 tmp[16] __attribute__((aligned(16)));
#pragma unroll
            for (int j = 0; j < 16; ++j) tmp[j] = (bf16)bp[(size_t)j * HID];
            *(bf16x8*)&Bs[bn][bkh]     = *(bf16x8*)tmp;
            *(bf16x8*)&Bs[bn][bkh + 8] = *(bf16x8*)(tmp + 8);
        }
        __syncthreads();
        bf16x8 a[4], b[4];
#pragma unroll
        for (int i = 0; i < 4; ++i) a[i] = *(const bf16x8*)&As[wm + i * 16 + fr][kq * 8];
#pragma unroll
        for (int j = 0; j < 4; ++j) b[j] = *(const bf16x8*)&Bs[wn + j * 16 + fr][kq * 8];
#pragma unroll
        for (int i = 0; i < 4; ++i)
#pragma unroll
            for (int j = 0; j < 4; ++j)
                acc[i][j] = __builtin_amdgcn_mfma_f32_16x16x32_bf16(a[i], b[j], acc[i][j], 0, 0, 0);
    }

    const int colBase = nt * 128 + wn;
#pragma unroll
    for (int i = 0; i < 4; ++i) {
#pragma unroll
        for (int r = 0; r < 4; ++r) {
            int mloc = wm + i * 16 + kq * 4 + r;
            int row = mt * 128 + mloc;
            if (row < cnt) {
                int tok = toks[mloc];
                float wgt = wts[mloc];
                float* dst = out + (size_t)tok * HID + colBase;
#pragma unroll
                for (int j = 0; j < 4; ++j)
                    atomicAdd(&dst[j * 16 + fr], acc[i][j][r] * wgt);
            }
        }
    }
}

extern "C" void kernel_launch(void* const* d_in, const int* in_sizes, int n_in,
                              void* d_out, int out_size, void* d_ws, size_t ws_size,
                              hipStream_t stream)
{
    const float* x  = (const float*)d_in[0];
    const float* gw = (const float*)d_in[1];
    const float* wg = (const float*)d_in[2];
    const float* wu = (const float*)d_in[3];
    const float* wd = (const float*)d_in[4];
    float* out    = (float*)d_out;
    float* logits = out + (size_t)T_TOK * HID;

    char* ws = (char*)d_ws;
    size_t o = 0;
    bf16* GU  = (bf16*)(ws + o); o += (size_t)16384 * 1536 * 2;  // 50.3 MB
    bf16* hdn = (bf16*)(ws + o); o += (size_t)16384 * 768 * 2;   // 25.2 MB
    int*   topi = (int*)(ws + o);        o += (size_t)T_TOK * TOPK * 4;
    float* topw = (float*)(ws + o);      o += (size_t)T_TOK * TOPK * 4;
    int*   slot_token = (int*)(ws + o);  o += (size_t)T_TOK * TOPK * 4;
    float* slot_w = (float*)(ws + o);    o += (size_t)T_TOK * TOPK * 4;
    int* counts  = (int*)(ws + o);
    int* offs    = counts + 32;
    int* cursors = counts + 64;

    hipMemsetAsync(out, 0, (size_t)T_TOK * HID * sizeof(float), stream);
    hipMemsetAsync(counts, 0, 32 * sizeof(int), stream);
    router_kernel<<<T_TOK, 256, 0, stream>>>(x, gw, logits, topi, topw, counts);
    offsets_kernel<<<1, 64, 0, stream>>>(counts, offs, cursors);
    scatter_kernel<<<T_TOK / 256, 256, 0, stream>>>(topi, topw, offs, cursors, slot_token, slot_w);
    gemm_gu_kernel<<<dim3(12, 32, 32), 256, 0, stream>>>(x, wg, wu, slot_token, offs, counts, GU);
    silu_mul_kernel<<<(16384 * 768 / 4) / 256, 256, 0, stream>>>(GU, hdn);
    gemm_down_kernel<<<dim3(16, 32, 32), 256, 0, stream>>>(hdn, wd, slot_token, slot_w, offs, counts, out);
}